// Round 12
// baseline (138.697 us; speedup 1.0000x reference)
//
#include <hip/hip_runtime.h>
#include <stdint.h>

typedef short bfrag __attribute__((ext_vector_type(8)));   // 8 bf16 = 4 VGPRs
typedef float f32x4 __attribute__((ext_vector_type(4)));
typedef uint  uint4v __attribute__((ext_vector_type(4)));
typedef uint  uint2v __attribute__((ext_vector_type(2)));

#define LOG2E 1.4426950408889634f
// LDS row swizzle: spreads rows {0-3 mod 8} AND consecutive rows across slots.
#define SWZ(row) ((((row) & 3) | (((row) >> 1) & 4)) << 4)

__device__ __forceinline__ ushort f2bf(float x){
  union { float f; uint32_t u; } c; c.f = x;
  uint32_t r = (c.u + 0x7fffu + ((c.u >> 16) & 1u)) >> 16;
  return (ushort)r;
}
__device__ __forceinline__ float bf2f(ushort u){
  union { uint32_t u; float f; } c; c.u = ((uint32_t)u) << 16;
  return c.f;
}

__device__ __forceinline__ uint32_t cvt_pk_bf16(float lo, float hi){
  uint32_t r;
  asm("v_cvt_pk_bf16_f32 %0, %1, %2" : "=v"(r) : "v"(lo), "v"(hi));
  return r;
}

// cross-lane reduce over lanes {lr, lr+16, lr+32, lr+48} — off the hot path.
__device__ __forceinline__ float redq_max(float x){
  x = fmaxf(x, __shfl_xor(x, 16));
  x = fmaxf(x, __shfl_xor(x, 32));
  return x;
}
__device__ __forceinline__ float redq_sum(float x){
  x += __shfl_xor(x, 16);
  x += __shfl_xor(x, 32);
  return x;
}

__device__ __forceinline__ void load_lds16(const void* g, void* l){
  __builtin_amdgcn_global_load_lds((const __attribute__((address_space(1))) void*)g,
                                   (__attribute__((address_space(3))) void*)l,
                                   16, 0, 0);
}

// Merged cast: hs|wqkv -> bf16 (contiguous), wout -> separate w2 buffer,
// mask*LOG2E -> f32.
__global__ void cast_all(const float* __restrict__ hs, const float* __restrict__ wqkv,
                         const float* __restrict__ wout, const float* __restrict__ mask,
                         ushort* __restrict__ out, ushort* __restrict__ w2,
                         float* __restrict__ mask2){
  const int i = blockIdx.x * blockDim.x + threadIdx.x;     // float4 index
  if (i < 2097152){
    float4 f;
    ushort4 u;
    if (i < 1048576)       f = ((const float4*)hs)[i];
    else if (i < 1835008)  f = ((const float4*)wqkv)[i - 1048576];
    else                   f = ((const float4*)wout)[i - 1835008];
    u.x = f2bf(f.x); u.y = f2bf(f.y); u.z = f2bf(f.z); u.w = f2bf(f.w);
    if (i < 1835008) ((ushort4*)out)[i] = u;
    else             ((ushort4*)w2)[i - 1835008] = u;
  } else {
    const int j = i - 2097152;                             // 1024 float4s of mask
    float4 m = ((const float4*)mask)[j];
    m.x *= LOG2E; m.y *= LOG2E; m.z *= LOG2E; m.w *= LOG2E;
    ((float4*)mask2)[j] = m;
  }
}

// C[m,n] = sum_k A[m,k]*B[n,k] + bias[n];  A:[M,K] bf16, B:[N,K] bf16, row-major.
// EPI==1: scatter bf16 into q/k [B*NH][S][HD] and V TRANSPOSED [B*NH][HD][S]
//         (packed 8B stores).  EPI==2: f32 dout[M][N].
template<int EPI>
__global__ __launch_bounds__(256)
void gemm_bt(const ushort* __restrict__ A, const ushort* __restrict__ B,
             const float* __restrict__ bias,
             ushort* __restrict__ dq, ushort* __restrict__ dk, ushort* __restrict__ dvt,
             float* __restrict__ dout,
             int M, int N, int K)
{
  __shared__ ushort Alds[2][128*32];
  __shared__ ushort Blds[2][128*32];
  const int t = threadIdx.x;
  const int w = t >> 6, l = t & 63;
  const int lr = l & 15, lg = l >> 4;
  const int m0 = blockIdx.x * 128, n0 = blockIdx.y * 128;
  const int wm = (w >> 1) * 64, wn = (w & 1) * 64;

  f32x4 acc[4][4] = {};

  auto stage = [&](int buf, int kt){
#pragma unroll
    for (int i = 0; i < 2; i++){
      const int row = i*64 + w*16 + (l >> 2);
      const int ce  = (l & 3) * 8;
      load_lds16(A + (size_t)(m0 + row) * K + kt*32 + ce, &Alds[buf][(i*64 + w*16) * 32]);
      load_lds16(B + (size_t)(n0 + row) * K + kt*32 + ce, &Blds[buf][(i*64 + w*16) * 32]);
    }
  };

  const int nk = K >> 5;
  int cur = 0;
  stage(0, 0);
  __syncthreads();
  for (int kt = 0; kt < nk; kt++){
    if (kt + 1 < nk) stage(cur ^ 1, kt + 1);
    bfrag af[4], bfv[4];
#pragma unroll
    for (int f = 0; f < 4; f++){
      af[f]  = *(const bfrag*)&Alds[cur][(wm + f*16 + lr) * 32 + lg * 8];
      bfv[f] = *(const bfrag*)&Blds[cur][(wn + f*16 + lr) * 32 + lg * 8];
    }
#pragma unroll
    for (int mf = 0; mf < 4; mf++)
#pragma unroll
      for (int nf = 0; nf < 4; nf++)
        acc[mf][nf] = __builtin_amdgcn_mfma_f32_16x16x32_bf16(af[mf], bfv[nf], acc[mf][nf], 0, 0, 0);
    __syncthreads();
    cur ^= 1;
  }

#pragma unroll
  for (int mf = 0; mf < 4; mf++){
#pragma unroll
    for (int nf = 0; nf < 4; nf++){
      const int col = n0 + wn + nf*16 + lr;
      const float bs = bias[col];
      if (EPI == 1){
        const int which = col >> 10;
        const int hd = col & 1023;
        const int bh = ((m0 >> 11) << 4) + (hd >> 6);   // m0 block is within one b
        const int s0 = (m0 + wm + mf*16 + lg*4) & 2047;
        if (which == 2){
          const float v0 = acc[mf][nf][0] + bs, v1 = acc[mf][nf][1] + bs;
          const float v2 = acc[mf][nf][2] + bs, v3 = acc[mf][nf][3] + bs;
          uint2v pv = { cvt_pk_bf16(v0, v1), cvt_pk_bf16(v2, v3) };
          *(uint2v*)(dvt + ((size_t)bh * 64 + (hd & 63)) * 2048 + s0) = pv;
        } else {
          ushort* dst = (which == 0) ? dq : dk;
#pragma unroll
          for (int r = 0; r < 4; r++)
            dst[((size_t)bh * 2048 + s0 + r) * 64 + (hd & 63)] = f2bf(acc[mf][nf][r] + bs);
        }
      } else {
#pragma unroll
        for (int r = 0; r < 4; r++){
          const int row = m0 + wm + mf*16 + lg*4 + r;
          dout[(size_t)row * N + col] = acc[mf][nf][r] + bs;
        }
      }
    }
  }
}

// Flash attention v12: v10 shape (4 waves, QBLK=128, 2 q-frags/wave) + KV
// SPLIT: blockIdx.z = half in {0,1}, each block covers 1024 keys (16 tiles).
// Grid (16,32,2) = 1024 blocks = 4/CU = 16 waves/CU. Each half writes a
// NORMALIZED partial O/l (bf16) + m,l (f32); merge_halves combines.
__global__ __launch_bounds__(256, 2)
void flash_attn(const ushort* __restrict__ q, const ushort* __restrict__ k,
                const ushort* __restrict__ vt, const float* __restrict__ mask2,
                ushort* __restrict__ opart, float* __restrict__ mpart,
                float* __restrict__ lpart)
{
  __shared__ ushort Klds[2][64*64];
  __shared__ ushort Vlds[2][64*64];
  const int t = threadIdx.x;
  const int w = t >> 6, l = t & 63;
  const int lr = l & 15, lg = l >> 4;
  const int bh = blockIdx.y;
  const int b = bh >> 4;
  const int z = blockIdx.z;
  const int q0 = blockIdx.x * 128;
  const int kvbase = z * 1024;
  const ushort* qb  = q  + (size_t)bh * 2048 * 64;
  const ushort* kb  = k  + (size_t)bh * 2048 * 64;
  const ushort* vtb = vt + (size_t)bh * 64 * 2048;
  const float* mb = mask2 + b * 2048;            // premultiplied by LOG2E

  const int srow0 = t >> 3;          // 0..31
  const int scol  = (t & 7) * 16;

  auto stageKV = [&](int buf, int kv0){
#pragma unroll
    for (int i = 0; i < 2; i++){
      const int row = srow0 + i*32;
      const int off = scol ^ SWZ(row);
      load_lds16((const char*)(kb + (size_t)kv0 * 64) + row*128 + off,
                 (char*)&Klds[buf][0] + i*4096 + w*1024);
      load_lds16((const char*)vtb + (size_t)row * 4096 + kv0*2 + off,
                 (char*)&Vlds[buf][0] + i*4096 + w*1024);
    }
  };

  bfrag qf[2][2];
#pragma unroll
  for (int qg = 0; qg < 2; qg++)
#pragma unroll
    for (int kf = 0; kf < 2; kf++){
      const int row = q0 + w*32 + qg*16 + lr;
      qf[qg][kf] = *(const bfrag*)(qb + (size_t)row * 64 + kf*32 + lg*8);
    }

  float mrun[2] = {-1e30f, -1e30f}, lsum[2] = {0.f, 0.f};
  f32x4 oacc[2][4] = {};

  const float SC2 = 0.125f * LOG2E;
  const int rbase = (lr >> 2) * 8 + (lr & 3);    // rho minus nf terms

  stageKV(0, kvbase);

  int cur = 0;
  for (int kv0 = kvbase; kv0 < kvbase + 1024; kv0 += 64){
    __syncthreads();               // drains prev prefetch + protects buffers
    if (kv0 + 64 < kvbase + 1024) stageKV(cur ^ 1, kv0 + 64);

    // mask for this lane's kv set: kv = (nf&1)*32 + lg*8 + (nf>>1)*4 + r
    float4 mk[4];
#pragma unroll
    for (int nf = 0; nf < 4; nf++)
      mk[nf] = *(const float4*)(mb + kv0 + ((nf & 1) << 5) + (lg << 3) + ((nf >> 1) << 2));

    // S^T = K Q^T with permuted K-row reads (shared across both q-groups)
    bfrag bk[4][2];
#pragma unroll
    for (int nf = 0; nf < 4; nf++){
      const int rho = ((nf & 1) << 5) + ((nf >> 1) << 2) + rbase;
      const int rsw = SWZ(rho);
#pragma unroll
      for (int kf = 0; kf < 2; kf++){
        const int kbyte = kf*64 + lg*16;
        bk[nf][kf] = *(const bfrag*)((const char*)&Klds[cur][0] + rho*128 + (kbyte ^ rsw));
      }
    }
    f32x4 sa[2][4] = {};
#pragma unroll
    for (int qg = 0; qg < 2; qg++)
#pragma unroll
      for (int nf = 0; nf < 4; nf++)
#pragma unroll
        for (int kf = 0; kf < 2; kf++)
          sa[qg][nf] = __builtin_amdgcn_mfma_f32_16x16x32_bf16(bk[nf][kf], qf[qg][kf], sa[qg][nf], 0, 0, 0);

    float sc[2][4][4], mx[2];
#pragma unroll
    for (int qg = 0; qg < 2; qg++){
#pragma unroll
      for (int nf = 0; nf < 4; nf++){
        sc[qg][nf][0] = fmaf(sa[qg][nf][0], SC2, mk[nf].x);
        sc[qg][nf][1] = fmaf(sa[qg][nf][1], SC2, mk[nf].y);
        sc[qg][nf][2] = fmaf(sa[qg][nf][2], SC2, mk[nf].z);
        sc[qg][nf][3] = fmaf(sa[qg][nf][3], SC2, mk[nf].w);
      }
      float m01 = fmaxf(fmaxf(sc[qg][0][0], sc[qg][0][1]), fmaxf(sc[qg][0][2], sc[qg][0][3]));
#pragma unroll
      for (int nf = 1; nf < 4; nf++)
#pragma unroll
        for (int r = 0; r < 4; r++) m01 = fmaxf(m01, sc[qg][nf][r]);
      mx[qg] = m01;
    }

    // defer-max (THR=8)
    const bool grew = (mx[0] > mrun[0] + 8.f) | (mx[1] > mrun[1] + 8.f);
    if (__any(grew)){
#pragma unroll
      for (int qg = 0; qg < 2; qg++){
        const float mnew = fmaxf(mrun[qg], redq_max(mx[qg]));
        const float c = __builtin_amdgcn_exp2f(mrun[qg] - mnew);
        mrun[qg] = mnew;
        lsum[qg] *= c;
#pragma unroll
        for (int nf = 0; nf < 4; nf++) oacc[qg][nf] *= c;
      }
    }

    // P = exp2(sc - mrun); partial sums; pack into PV B-fragments
    bfrag ap[2][2];
#pragma unroll
    for (int qg = 0; qg < 2; qg++){
      float ps = 0.f;
#pragma unroll
      for (int nf = 0; nf < 4; nf++)
#pragma unroll
        for (int r = 0; r < 4; r++){
          sc[qg][nf][r] = __builtin_amdgcn_exp2f(sc[qg][nf][r] - mrun[qg]);
          ps += sc[qg][nf][r];
        }
      lsum[qg] += ps;
#pragma unroll
      for (int kf = 0; kf < 2; kf++){
        uint4v tv = { cvt_pk_bf16(sc[qg][kf][0],   sc[qg][kf][1]),
                      cvt_pk_bf16(sc[qg][kf][2],   sc[qg][kf][3]),
                      cvt_pk_bf16(sc[qg][kf+2][0], sc[qg][kf+2][1]),
                      cvt_pk_bf16(sc[qg][kf+2][2], sc[qg][kf+2][3]) };
        ap[qg][kf] = __builtin_bit_cast(bfrag, tv);
      }
    }

    // O^T += Vt P (bv shared across q-groups)
    bfrag bv[4][2];
#pragma unroll
    for (int nf = 0; nf < 4; nf++)
#pragma unroll
      for (int kf = 0; kf < 2; kf++){
        const int d = nf*16 + lr;
        const int kbyte = kf*64 + lg*16;
        bv[nf][kf] = *(const bfrag*)((const char*)&Vlds[cur][0] + d*128 + (kbyte ^ SWZ(d)));
      }
#pragma unroll
    for (int qg = 0; qg < 2; qg++)
#pragma unroll
      for (int nf = 0; nf < 4; nf++)
#pragma unroll
        for (int kf = 0; kf < 2; kf++)
          oacc[qg][nf] = __builtin_amdgcn_mfma_f32_16x16x32_bf16(bv[nf][kf], ap[qg][kf], oacc[qg][nf], 0, 0, 0);

    cur ^= 1;
  }

  // epilogue per q-group: normalized partial O/l (bf16) + m, l (f32)
#pragma unroll
  for (int qg = 0; qg < 2; qg++){
    const int row = q0 + w*32 + qg*16 + lr;
    const float ltot = redq_sum(lsum[qg]);
    const float inv = 1.f / ltot;
    if (lg == 0){
      mpart[((size_t)z*32 + bh)*2048 + row] = mrun[qg];
      lpart[((size_t)z*32 + bh)*2048 + row] = ltot;
    }
    ushort* orow = opart + (size_t)z*16777216/2 + ((size_t)bh*2048 + row)*64 + lg*4;
#pragma unroll
    for (int nf = 0; nf < 4; nf++){
      const uint32_t w01 = cvt_pk_bf16(oacc[qg][nf][0] * inv, oacc[qg][nf][1] * inv);
      const uint32_t w23 = cvt_pk_bf16(oacc[qg][nf][2] * inv, oacc[qg][nf][3] * inv);
      uint2v vv = {w01, w23};
      *(uint2v*)(orow + nf*16) = vv;
    }
  }
}

// Combine the two KV-half partials: out = c0*O^0 + c1*O^1,
// c_i = w_i l_i / (w0 l0 + w1 l1), w_i = 2^(m_i - m).
__global__ __launch_bounds__(256)
void merge_halves(const ushort* __restrict__ opart, const float* __restrict__ mpart,
                  const float* __restrict__ lpart, ushort* __restrict__ ao){
  const int idx = blockIdx.x * 256 + threadIdx.x;   // 8 cols per thread
  const int row = idx >> 7;
  const int col0 = (idx & 127) * 8;
  const int h = col0 >> 6;
  const int b = row >> 11, s = row & 2047;
  const int bh = b*16 + h;
  const float m0 = mpart[(size_t)bh*2048 + s], m1 = mpart[(size_t)(32+bh)*2048 + s];
  const float l0 = lpart[(size_t)bh*2048 + s], l1 = lpart[(size_t)(32+bh)*2048 + s];
  const float m = fmaxf(m0, m1);
  const float a0 = __builtin_amdgcn_exp2f(m0 - m) * l0;
  const float a1 = __builtin_amdgcn_exp2f(m1 - m) * l1;
  const float inv = 1.f / (a0 + a1);
  const float c0 = a0 * inv, c1 = a1 * inv;
  const size_t pix = ((size_t)bh*2048 + s)*64 + (col0 & 63);
  bfrag f0 = *(const bfrag*)(opart + pix);
  bfrag f1 = *(const bfrag*)(opart + 8388608 + pix);
  uint32_t wds[4];
#pragma unroll
  for (int j = 0; j < 4; j++){
    const float x0 = c0*bf2f((ushort)f0[2*j  ]) + c1*bf2f((ushort)f1[2*j  ]);
    const float x1 = c0*bf2f((ushort)f0[2*j+1]) + c1*bf2f((ushort)f1[2*j+1]);
    wds[j] = cvt_pk_bf16(x0, x1);
  }
  uint4v vv = {wds[0], wds[1], wds[2], wds[3]};
  *(uint4v*)(ao + (size_t)row*1024 + col0) = vv;
}

extern "C" void kernel_launch(void* const* d_in, const int* in_sizes, int n_in,
                              void* d_out, int out_size, void* d_ws, size_t ws_size,
                              hipStream_t stream)
{
  (void)in_sizes; (void)n_in; (void)out_size; (void)ws_size;
  const float* hs   = (const float*)d_in[0];
  const float* mask = (const float*)d_in[1];
  const float* wqkv = (const float*)d_in[2];
  const float* bqkv = (const float*)d_in[3];
  const float* wout = (const float*)d_in[4];
  const float* bout = (const float*)d_in[5];
  float* out = (float*)d_out;

  char* ws = (char*)d_ws;
  // 0..16MB:   hs_bf(8) + w1_bf(6) during cast/gemm1; REUSED as opart (16MB,
  //            two 8MB halves [z][bh][s][64] bf16) by flash (after gemm1).
  ushort* hs_bf = (ushort*)(ws);
  ushort* w1_bf = (ushort*)(ws + 8388608);
  ushort* opart = (ushort*)(ws);
  ushort* q_bf  = (ushort*)(ws + 16777216);      // [32][2048][64] bf16 (8 MB)
  ushort* k_bf  = (ushort*)(ws + 25165824);      // [32][2048][64] bf16 (8 MB)
  ushort* vt_bf = (ushort*)(ws + 33554432);      // [32][64][2048] bf16 (8 MB)
  ushort* ao_bf = (ushort*)(ws + 41943040);      // [4096][1024] bf16 (8 MB)
  float*  mpart = (float*)(ws + 50331648);       // [2][32][2048] f32 (512 KB)
  float*  lpart = (float*)(ws + 50855936);       // [2][32][2048] f32 (512 KB)
  float*  mask2 = (float*)(ws + 51380224);       // [2][2048] f32 (16 KB)
  ushort* w2_bf = (ushort*)(ws + 51396608);      // 1024*1024 bf16 (2 MB)

  cast_all<<<8196, 256, 0, stream>>>(hs, wqkv, wout, mask, (ushort*)ws, w2_bf, mask2);

  gemm_bt<1><<<dim3(32, 24), 256, 0, stream>>>(hs_bf, w1_bf, bqkv,
                                               q_bf, k_bf, vt_bf, nullptr,
                                               4096, 3072, 1024);
  flash_attn<<<dim3(16, 32, 2), 256, 0, stream>>>(q_bf, k_bf, vt_bf, mask2,
                                                  opart, mpart, lpart);
  merge_halves<<<2048, 256, 0, stream>>>(opart, mpart, lpart, ao_bf);
  gemm_bt<2><<<dim3(32, 8), 256, 0, stream>>>(ao_bf, w2_bf, bout,
                                              nullptr, nullptr, nullptr, out,
                                              4096, 1024, 1024);
}

// Round 15
// 122.243 us; speedup vs baseline: 1.1346x; 1.1346x over previous
//
#include <hip/hip_runtime.h>
#include <stdint.h>

typedef short bfrag __attribute__((ext_vector_type(8)));   // 8 bf16 = 4 VGPRs
typedef float f32x4 __attribute__((ext_vector_type(4)));
typedef uint  uint4v __attribute__((ext_vector_type(4)));
typedef uint  uint2v __attribute__((ext_vector_type(2)));

#define LOG2E 1.4426950408889634f
// LDS row swizzle: spreads rows {0-3 mod 8} AND consecutive rows across slots.
#define SWZ(row) ((((row) & 3) | (((row) >> 1) & 4)) << 4)

__device__ __forceinline__ ushort f2bf(float x){
  union { float f; uint32_t u; } c; c.f = x;
  uint32_t r = (c.u + 0x7fffu + ((c.u >> 16) & 1u)) >> 16;
  return (ushort)r;
}

__device__ __forceinline__ uint32_t cvt_pk_bf16(float lo, float hi){
  uint32_t r;
  asm("v_cvt_pk_bf16_f32 %0, %1, %2" : "=v"(r) : "v"(lo), "v"(hi));
  return r;
}

// cross-lane reduce over lanes {lr, lr+16, lr+32, lr+48} — off the hot path.
__device__ __forceinline__ float redq_max(float x){
  x = fmaxf(x, __shfl_xor(x, 16));
  x = fmaxf(x, __shfl_xor(x, 32));
  return x;
}
__device__ __forceinline__ float redq_sum(float x){
  x += __shfl_xor(x, 16);
  x += __shfl_xor(x, 32);
  return x;
}

__device__ __forceinline__ void load_lds16(const void* g, void* l){
  __builtin_amdgcn_global_load_lds((const __attribute__((address_space(1))) void*)g,
                                   (__attribute__((address_space(3))) void*)l,
                                   16, 0, 0);
}

// Merged cast: hs|wqkv|wout -> bf16 (contiguous in ws), plus mask*LOG2E -> f32.
__global__ void cast_all(const float* __restrict__ hs, const float* __restrict__ wqkv,
                         const float* __restrict__ wout, const float* __restrict__ mask,
                         ushort* __restrict__ out, float* __restrict__ mask2){
  const int i = blockIdx.x * blockDim.x + threadIdx.x;     // float4 index
  if (i < 2097152){
    float4 f;
    if (i < 1048576)       f = ((const float4*)hs)[i];
    else if (i < 1835008)  f = ((const float4*)wqkv)[i - 1048576];
    else                   f = ((const float4*)wout)[i - 1835008];
    ushort4 u;
    u.x = f2bf(f.x); u.y = f2bf(f.y); u.z = f2bf(f.z); u.w = f2bf(f.w);
    ((ushort4*)out)[i] = u;
  } else {
    const int j = i - 2097152;                             // 1024 float4s of mask
    float4 m = ((const float4*)mask)[j];
    m.x *= LOG2E; m.y *= LOG2E; m.z *= LOG2E; m.w *= LOG2E;
    ((float4*)mask2)[j] = m;
  }
}

// C[m,n] = sum_k A[m,k]*B[n,k] + bias[n];  A:[M,K] bf16, B:[N,K] bf16, row-major.
// EPI==1: scatter bf16 into q/k [B*NH][S][HD] and V TRANSPOSED [B*NH][HD][S]
//         (packed 8B stores).  EPI==2: f32 dout[M][N].
// T1: XCD-bijective block swizzle (nwg % 8 == 0 for both grids used).
template<int EPI>
__global__ __launch_bounds__(256)
void gemm_bt(const ushort* __restrict__ A, const ushort* __restrict__ B,
             const float* __restrict__ bias,
             ushort* __restrict__ dq, ushort* __restrict__ dk, ushort* __restrict__ dvt,
             float* __restrict__ dout,
             int M, int N, int K)
{
  __shared__ ushort Alds[2][128*32];
  __shared__ ushort Blds[2][128*32];
  const int t = threadIdx.x;
  const int w = t >> 6, l = t & 63;
  const int lr = l & 15, lg = l >> 4;
  // XCD swizzle: consecutive-linear blocks (same n-tile row) land on ONE XCD.
  const int nwg = gridDim.x * gridDim.y;
  const int cpx = nwg >> 3;
  const int lin = blockIdx.y * gridDim.x + blockIdx.x;
  const int swz = (lin & 7) * cpx + (lin >> 3);
  const int m0 = (swz % gridDim.x) * 128, n0 = (swz / gridDim.x) * 128;
  const int wm = (w >> 1) * 64, wn = (w & 1) * 64;

  f32x4 acc[4][4] = {};

  auto stage = [&](int buf, int kt){
#pragma unroll
    for (int i = 0; i < 2; i++){
      const int row = i*64 + w*16 + (l >> 2);
      const int ce  = (l & 3) * 8;
      load_lds16(A + (size_t)(m0 + row) * K + kt*32 + ce, &Alds[buf][(i*64 + w*16) * 32]);
      load_lds16(B + (size_t)(n0 + row) * K + kt*32 + ce, &Blds[buf][(i*64 + w*16) * 32]);
    }
  };

  const int nk = K >> 5;
  int cur = 0;
  stage(0, 0);
  __syncthreads();
  for (int kt = 0; kt < nk; kt++){
    if (kt + 1 < nk) stage(cur ^ 1, kt + 1);
    bfrag af[4], bfv[4];
#pragma unroll
    for (int f = 0; f < 4; f++){
      af[f]  = *(const bfrag*)&Alds[cur][(wm + f*16 + lr) * 32 + lg * 8];
      bfv[f] = *(const bfrag*)&Blds[cur][(wn + f*16 + lr) * 32 + lg * 8];
    }
#pragma unroll
    for (int mf = 0; mf < 4; mf++)
#pragma unroll
      for (int nf = 0; nf < 4; nf++)
        acc[mf][nf] = __builtin_amdgcn_mfma_f32_16x16x32_bf16(af[mf], bfv[nf], acc[mf][nf], 0, 0, 0);
    __syncthreads();
    cur ^= 1;
  }

#pragma unroll
  for (int mf = 0; mf < 4; mf++){
#pragma unroll
    for (int nf = 0; nf < 4; nf++){
      const int col = n0 + wn + nf*16 + lr;
      const float bs = bias[col];
      if (EPI == 1){
        const int which = col >> 10;
        const int hd = col & 1023;
        const int bh = ((m0 >> 11) << 4) + (hd >> 6);   // m0 block is within one b
        const int s0 = (m0 + wm + mf*16 + lg*4) & 2047;
        if (which == 2){
          const float v0 = acc[mf][nf][0] + bs, v1 = acc[mf][nf][1] + bs;
          const float v2 = acc[mf][nf][2] + bs, v3 = acc[mf][nf][3] + bs;
          uint2v pv = { cvt_pk_bf16(v0, v1), cvt_pk_bf16(v2, v3) };
          *(uint2v*)(dvt + ((size_t)bh * 64 + (hd & 63)) * 2048 + s0) = pv;
        } else {
          ushort* dst = (which == 0) ? dq : dk;
#pragma unroll
          for (int r = 0; r < 4; r++)
            dst[((size_t)bh * 2048 + s0 + r) * 64 + (hd & 63)] = f2bf(acc[mf][nf][r] + bs);
        }
      } else {
#pragma unroll
        for (int r = 0; r < 4; r++){
          const int row = m0 + wm + mf*16 + lg*4 + r;
          dout[(size_t)row * N + col] = acc[mf][nf][r] + bs;
        }
      }
    }
  }
}

// Flash attention v15 = v10 EXACT structure (proven 6 rounds) + two zero-risk
// scheduling changes: (a) T1 XCD-bijective block swizzle so the 16 q-blocks
// sharing one bh's K/V land on one XCD (K/V L2-resident: 4 bh x 512KB = 2MB
// < 4MB XCD L2; cuts the 69.7MB vs 24MB ideal FETCH duplication); (b) T5
// s_setprio(1) around the QK and PV MFMA clusters (m191: attn +4-7%).
// Math, staging, sync structure byte-identical to v10.
__global__ __launch_bounds__(256, 2)
void flash_attn(const ushort* __restrict__ q, const ushort* __restrict__ k,
                const ushort* __restrict__ vt, const float* __restrict__ mask2,
                ushort* __restrict__ ao)
{
  __shared__ ushort Klds[2][64*64];
  __shared__ ushort Vlds[2][64*64];
  const int t = threadIdx.x;
  const int w = t >> 6, l = t & 63;
  const int lr = l & 15, lg = l >> 4;
  // T1 swizzle: lin in [0,512); chunk of 64 consecutive lins -> one XCD
  // = 4 complete bh's worth of q-blocks.
  const int lin = blockIdx.y * 16 + blockIdx.x;
  const int swz = (lin & 7) * 64 + (lin >> 3);
  const int bh = swz >> 4;
  const int b = bh >> 4, h = bh & 15;
  const int q0 = (swz & 15) * 128;
  const ushort* qb  = q  + (size_t)bh * 2048 * 64;
  const ushort* kb  = k  + (size_t)bh * 2048 * 64;
  const ushort* vtb = vt + (size_t)bh * 64 * 2048;
  const float* mb = mask2 + b * 2048;            // premultiplied by LOG2E

  const int srow0 = t >> 3;          // 0..31
  const int scol  = (t & 7) * 16;

  auto stageKV = [&](int buf, int kv0){
#pragma unroll
    for (int i = 0; i < 2; i++){
      const int row = srow0 + i*32;
      const int off = scol ^ SWZ(row);
      load_lds16((const char*)(kb + (size_t)kv0 * 64) + row*128 + off,
                 (char*)&Klds[buf][0] + i*4096 + w*1024);
      load_lds16((const char*)vtb + (size_t)row * 4096 + kv0*2 + off,
                 (char*)&Vlds[buf][0] + i*4096 + w*1024);
    }
  };

  bfrag qf[2][2];
#pragma unroll
  for (int qg = 0; qg < 2; qg++)
#pragma unroll
    for (int kf = 0; kf < 2; kf++){
      const int row = q0 + w*32 + qg*16 + lr;
      qf[qg][kf] = *(const bfrag*)(qb + (size_t)row * 64 + kf*32 + lg*8);
    }

  float mrun[2] = {-1e30f, -1e30f}, lsum[2] = {0.f, 0.f};
  f32x4 oacc[2][4] = {};

  const float SC2 = 0.125f * LOG2E;
  const int rbase = (lr >> 2) * 8 + (lr & 3);    // rho minus nf terms

  stageKV(0, 0);

  int cur = 0;
  for (int kv0 = 0; kv0 < 2048; kv0 += 64){
    __syncthreads();               // drains prev prefetch + protects buffers
    if (kv0 + 64 < 2048) stageKV(cur ^ 1, kv0 + 64);

    // mask for this lane's kv set: kv = (nf&1)*32 + lg*8 + (nf>>1)*4 + r
    float4 mk[4];
#pragma unroll
    for (int nf = 0; nf < 4; nf++)
      mk[nf] = *(const float4*)(mb + kv0 + ((nf & 1) << 5) + (lg << 3) + ((nf >> 1) << 2));

    // S^T = K Q^T with permuted K-row reads (shared across both q-groups)
    bfrag bk[4][2];
#pragma unroll
    for (int nf = 0; nf < 4; nf++){
      const int rho = ((nf & 1) << 5) + ((nf >> 1) << 2) + rbase;
      const int rsw = SWZ(rho);
#pragma unroll
      for (int kf = 0; kf < 2; kf++){
        const int kbyte = kf*64 + lg*16;
        bk[nf][kf] = *(const bfrag*)((const char*)&Klds[cur][0] + rho*128 + (kbyte ^ rsw));
      }
    }
    f32x4 sa[2][4] = {};
    __builtin_amdgcn_s_setprio(1);
#pragma unroll
    for (int qg = 0; qg < 2; qg++)
#pragma unroll
      for (int nf = 0; nf < 4; nf++)
#pragma unroll
        for (int kf = 0; kf < 2; kf++)
          sa[qg][nf] = __builtin_amdgcn_mfma_f32_16x16x32_bf16(bk[nf][kf], qf[qg][kf], sa[qg][nf], 0, 0, 0);
    __builtin_amdgcn_s_setprio(0);

    // scaled scores (exp2 domain); per-lane max over own 16 k's per q-group
    float sc[2][4][4], mx[2];
#pragma unroll
    for (int qg = 0; qg < 2; qg++){
#pragma unroll
      for (int nf = 0; nf < 4; nf++){
        sc[qg][nf][0] = fmaf(sa[qg][nf][0], SC2, mk[nf].x);
        sc[qg][nf][1] = fmaf(sa[qg][nf][1], SC2, mk[nf].y);
        sc[qg][nf][2] = fmaf(sa[qg][nf][2], SC2, mk[nf].z);
        sc[qg][nf][3] = fmaf(sa[qg][nf][3], SC2, mk[nf].w);
      }
      float m01 = fmaxf(fmaxf(sc[qg][0][0], sc[qg][0][1]), fmaxf(sc[qg][0][2], sc[qg][0][3]));
#pragma unroll
      for (int nf = 1; nf < 4; nf++)
#pragma unroll
        for (int r = 0; r < 4; r++) m01 = fmaxf(m01, sc[qg][nf][r]);
      mx[qg] = m01;
    }

    // defer-max (THR=8)
    const bool grew = (mx[0] > mrun[0] + 8.f) | (mx[1] > mrun[1] + 8.f);
    if (__any(grew)){
#pragma unroll
      for (int qg = 0; qg < 2; qg++){
        const float mnew = fmaxf(mrun[qg], redq_max(mx[qg]));
        const float c = __builtin_amdgcn_exp2f(mrun[qg] - mnew);
        mrun[qg] = mnew;
        lsum[qg] *= c;
#pragma unroll
        for (int nf = 0; nf < 4; nf++) oacc[qg][nf] *= c;
      }
    }

    // P = exp2(sc - mrun) in place; partial sums; pack into PV B-fragments
    bfrag ap[2][2];
#pragma unroll
    for (int qg = 0; qg < 2; qg++){
      float ps = 0.f;
#pragma unroll
      for (int nf = 0; nf < 4; nf++)
#pragma unroll
        for (int r = 0; r < 4; r++){
          sc[qg][nf][r] = __builtin_amdgcn_exp2f(sc[qg][nf][r] - mrun[qg]);
          ps += sc[qg][nf][r];
        }
      lsum[qg] += ps;
#pragma unroll
      for (int kf = 0; kf < 2; kf++){
        uint4v tv = { cvt_pk_bf16(sc[qg][kf][0],   sc[qg][kf][1]),
                      cvt_pk_bf16(sc[qg][kf][2],   sc[qg][kf][3]),
                      cvt_pk_bf16(sc[qg][kf+2][0], sc[qg][kf+2][1]),
                      cvt_pk_bf16(sc[qg][kf+2][2], sc[qg][kf+2][3]) };
        ap[qg][kf] = __builtin_bit_cast(bfrag, tv);
      }
    }

    // O^T += Vt P (bv shared across q-groups)
    bfrag bv[4][2];
#pragma unroll
    for (int nf = 0; nf < 4; nf++)
#pragma unroll
      for (int kf = 0; kf < 2; kf++){
        const int d = nf*16 + lr;
        const int kbyte = kf*64 + lg*16;
        bv[nf][kf] = *(const bfrag*)((const char*)&Vlds[cur][0] + d*128 + (kbyte ^ SWZ(d)));
      }
    __builtin_amdgcn_s_setprio(1);
#pragma unroll
    for (int qg = 0; qg < 2; qg++)
#pragma unroll
      for (int nf = 0; nf < 4; nf++)
#pragma unroll
        for (int kf = 0; kf < 2; kf++)
          oacc[qg][nf] = __builtin_amdgcn_mfma_f32_16x16x32_bf16(bv[nf][kf], ap[qg][kf], oacc[qg][nf], 0, 0, 0);
    __builtin_amdgcn_s_setprio(0);

    cur ^= 1;
  }

  // epilogue per q-group: finish row-sum, divide, store 8B
#pragma unroll
  for (int qg = 0; qg < 2; qg++){
    const float inv = 1.f / redq_sum(lsum[qg]);
    ushort* orow = ao + (size_t)(b*2048 + q0 + w*32 + qg*16 + lr) * 1024 + h*64 + lg*4;
#pragma unroll
    for (int nf = 0; nf < 4; nf++){
      const uint32_t w01 = cvt_pk_bf16(oacc[qg][nf][0] * inv, oacc[qg][nf][1] * inv);
      const uint32_t w23 = cvt_pk_bf16(oacc[qg][nf][2] * inv, oacc[qg][nf][3] * inv);
      uint2v vv = {w01, w23};
      *(uint2v*)(orow + nf*16) = vv;
    }
  }
}

extern "C" void kernel_launch(void* const* d_in, const int* in_sizes, int n_in,
                              void* d_out, int out_size, void* d_ws, size_t ws_size,
                              hipStream_t stream)
{
  (void)in_sizes; (void)n_in; (void)out_size; (void)ws_size;
  const float* hs   = (const float*)d_in[0];
  const float* mask = (const float*)d_in[1];
  const float* wqkv = (const float*)d_in[2];
  const float* bqkv = (const float*)d_in[3];
  const float* wout = (const float*)d_in[4];
  const float* bout = (const float*)d_in[5];
  float* out = (float*)d_out;

  char* ws = (char*)d_ws;
  ushort* hs_bf = (ushort*)(ws);                 // 4096*1024   bf16 (8 MB)
  ushort* w1_bf = (ushort*)(ws + 8388608);       // 3072*1024   bf16 (6 MB)
  ushort* w2_bf = (ushort*)(ws + 14680064);      // 1024*1024   bf16 (2 MB)
  ushort* q_bf  = (ushort*)(ws + 16777216);      // [32][2048][64] bf16 (8 MB)
  ushort* k_bf  = (ushort*)(ws + 25165824);      // [32][2048][64] bf16 (8 MB)
  ushort* vt_bf = (ushort*)(ws + 33554432);      // [32][64][2048] bf16 (8 MB)
  ushort* ao_bf = (ushort*)(ws + 41943040);      // [4096][1024] bf16 (8 MB)
  float*  mask2 = (float*)(ws + 50331648);       // [2][2048] f32 * LOG2E (16 KB)

  cast_all<<<8196, 256, 0, stream>>>(hs, wqkv, wout, mask, (ushort*)ws, mask2);

  gemm_bt<1><<<dim3(32, 24), 256, 0, stream>>>(hs_bf, w1_bf, bqkv,
                                               q_bf, k_bf, vt_bf, nullptr,
                                               4096, 3072, 1024);
  flash_attn<<<dim3(16, 32), 256, 0, stream>>>(q_bf, k_bf, vt_bf, mask2, ao_bf);
  gemm_bt<2><<<dim3(32, 8), 256, 0, stream>>>(ao_bf, w2_bf, bout,
                                              nullptr, nullptr, nullptr, out,
                                              4096, 1024, 1024);
}